// Round 10
// baseline (2710.840 us; speedup 1.0000x reference)
//
#include <hip/hip_runtime.h>
#include <hip/hip_bf16.h>
#include <cstdint>
#include <cstddef>

#define BB 64
#define SS 512
#define DD 1024
#define G4 4096  // 4*units

typedef __attribute__((ext_vector_type(8))) short bf16x8;
typedef __attribute__((ext_vector_type(8))) unsigned short u16x8;
typedef __attribute__((ext_vector_type(4))) float f32x4;

static __device__ __forceinline__ unsigned short f2bf(float f) {
  union { float f; uint32_t u; } v; v.f = f;
  uint32_t u = v.u;
  return (unsigned short)((u + 0x7FFFu + ((u >> 16) & 1u)) >> 16);  // RTNE
}
static __device__ __forceinline__ float bf2f(unsigned short s) {
  union { uint32_t u; float f; } v; v.u = ((uint32_t)s) << 16; return v.f;
}

typedef __attribute__((address_space(1))) const unsigned int kGlbU32;
typedef __attribute__((address_space(3))) unsigned int kLdsU32;
static __device__ __forceinline__ void gload_lds16(const void* g, void* l) {
  __builtin_amdgcn_global_load_lds((kGlbU32*)g, (kLdsU32*)l, 16, 0, 0);
}

// ---- convert x (f32 -> bf16), vectorized ----
__global__ void cvt_x(const float* __restrict__ in, unsigned short* __restrict__ out, int n8) {
  for (int i = blockIdx.x * blockDim.x + threadIdx.x; i < n8; i += gridDim.x * blockDim.x) {
    const float4* pp = (const float4*)(in + (size_t)i * 8);
    float4 a = pp[0], b2 = pp[1];
    u16x8 o;
    o[0] = f2bf(a.x);  o[1] = f2bf(a.y);  o[2] = f2bf(a.z);  o[3] = f2bf(a.w);
    o[4] = f2bf(b2.x); o[5] = f2bf(b2.y); o[6] = f2bf(b2.z); o[7] = f2bf(b2.w);
    *(u16x8*)(out + (size_t)i * 8) = o;
  }
}

// ---- transpose-convert W,U: in[k][c] f32 -> out[c][k] bf16 ----
__global__ __launch_bounds__(256) void cvt_transpose(
    const float* __restrict__ Win, const float* __restrict__ Uin,
    unsigned short* __restrict__ Wt, unsigned short* __restrict__ Ut) {
  __shared__ float tile[32][33];
  const float* in = blockIdx.z ? Uin : Win;
  unsigned short* out = blockIdx.z ? Ut : Wt;
  int k0 = blockIdx.x * 32;
  int c0 = blockIdx.y * 32;
  int tc = threadIdx.x & 31, tr = threadIdx.x >> 5;
  #pragma unroll
  for (int j = 0; j < 32; j += 8)
    tile[tr + j][tc] = in[(size_t)(k0 + tr + j) * G4 + (c0 + tc)];
  __syncthreads();
  #pragma unroll
  for (int j = 0; j < 32; j += 8)
    out[(size_t)(c0 + tr + j) * DD + (k0 + tc)] = f2bf(tile[tc][tr + j]);
}

// ---- pack [col][k] bf16 matrix into MFMA B-fragment order (used for U and W) ----
__global__ __launch_bounds__(256) void pack_u(const unsigned short* __restrict__ Ut,
                                              unsigned short* __restrict__ Up) {
  int tid = blockIdx.x * 256 + threadIdx.x;  // 64*4*32*64 = 524288 total
  int l = tid & 63;
  int kk = (tid >> 6) & 31;
  int g = (tid >> 11) & 3;
  int u = tid >> 13;
  int col = g * DD + u * 16 + (l & 15);
  int k = kk * 32 + (l >> 4) * 8;
  bf16x8 v = *(const bf16x8*)(Ut + (size_t)col * DD + k);
  *(bf16x8*)(Up + (size_t)tid * 8) = v;
}

// ---- persistent recurrence kernel: 256 wgs (1/CU), U in LDS, W fused ----
// z_t = x_t@W + h_{t-1}@U + b.  The x@W part is computed INSIDE the idle
// handoff window (signal-early / consume-late): flag stored before the xW
// phase; xW MFMAs + L2-resident W loads fill the spin time; Uh consumption
// (r7's proven 4-batch counted pipeline) runs after.
// LDS (156 KB): [0,122880) Up 4w x 30frags | [122880,+32K) xs | [155648,+4K) zt
__global__ __launch_bounds__(256, 1) void lstm_persist(
    const unsigned short* __restrict__ xb,   // bf16 [B][S][D]
    const unsigned short* __restrict__ Up,   // packed U B-frags
    const unsigned short* __restrict__ Wp,   // packed W B-frags
    unsigned short* __restrict__ h0,         // packed h A-frags [4][32][64][8]
    unsigned short* __restrict__ h1,
    unsigned int* __restrict__ bar,          // flags[4][64] dwords, zeroed
    const float* __restrict__ bias,
    float* __restrict__ out) {
  extern __shared__ char smem[];
  const int bid = blockIdx.x;
  const int rgrp = (bid & 7) >> 1;             // XCD-pair-friendly mapping
  const int ugrp = (bid >> 3) * 2 + (bid & 1);
  const int tid = threadIdx.x;
  const int wave = tid >> 6, lane = tid & 63;
  // gate-element mapping (h-store tid-contiguous; verified r9)
  const int row = (tid >> 3) & 15;             // batch row within rgrp
  const int uc = (tid >> 7) * 8 + (tid & 7);   // unit within ugrp
  const int unit = ugrp * 16 + uc;
  const int grow = rgrp * 16 + row;            // global batch row

  char* upw = smem + wave * 30720;             // this wave's 30 U-frags
  char* xs  = smem + 122880;                   // 32 KB x slice (staged per step)
  float (*zt)[16][16] = (float (*)[16][16])(smem + 155648);

  // one-time: stage this wave's U fragments (30 to LDS, 2 to regs)
  const char* ug = (const char*)Up + (size_t)(ugrp * 4 + wave) * 32768;
  #pragma unroll
  for (int kk = 0; kk < 30; ++kk)
    gload_lds16(ug + kk * 1024 + lane * 16, upw + kk * 1024 + lane * 16);
  bf16x8 u30 = *(const bf16x8*)(ug + 30 * 1024 + lane * 16);
  bf16x8 u31 = *(const bf16x8*)(ug + 31 * 1024 + lane * 16);
  const char* wgb = (const char*)Wp + (size_t)(ugrp * 4 + wave) * 32768;

  const float bi0 = bias[unit], bi1 = bias[DD + unit],
              bi2 = bias[2 * DD + unit], bi3 = bias[3 * DD + unit];

  const size_t hoff = (size_t)rgrp * 16384 + (size_t)(ugrp >> 1) * 512 +
                      (size_t)(ugrp & 1) * 256 + tid;
  unsigned int* myflags = bar + rgrp * 64;     // 64 dwords, one per producer
  float c = 0.f;

// stage x_t slice (16 rows x 1024) into xs, source pre-swizzled so the
// swizzled ds_read is conflict-reduced (rule #21: linear dest + inv-swz src)
#define STAGE_X(TT)                                                            \
  {                                                                            \
    _Pragma("unroll")                                                          \
    for (int i = 0; i < 8; ++i) {                                              \
      const int ch = wave * 8 + i;                                             \
      const int xrow = ch >> 1;                                                \
      const int kbyte = (ch & 1) * 1024 + lane * 16;                           \
      const int ksw = kbyte ^ ((xrow & 7) << 4);                               \
      const char* src = (const char*)xb +                                      \
          ((size_t)(rgrp * 16 + xrow) * SS + (TT)) * 2048 + ksw;               \
      gload_lds16(src, xs + ch * 1024 + lane * 16);                            \
    }                                                                          \
  }

// xW phase: 32 MFMA (A = x-frags from swizzled xs, B = W-frags from L2)
#define XW_COMPUTE(ZXOUT)                                                      \
  {                                                                            \
    f32x4 x0 = {0.f, 0.f, 0.f, 0.f}, x1 = x0, x2 = x0, x3 = x0;                \
    _Pragma("unroll")                                                          \
    for (int half = 0; half < 2; ++half) {                                     \
      bf16x8 wv[16];                                                           \
      _Pragma("unroll")                                                        \
      for (int i = 0; i < 16; ++i)                                             \
        wv[i] = *(const bf16x8*)(wgb + (half * 16 + i) * 1024 + lane * 16);    \
      _Pragma("unroll")                                                        \
      for (int i = 0; i < 16; i += 4) {                                        \
        const int kk = half * 16 + i;                                          \
        const int arow = (lane & 15) * 2048;                                   \
        const int swz = (lane & 7) << 4;                                       \
        bf16x8 af0 = *(const bf16x8*)(xs + arow + (((kk + 0) * 64 + (lane >> 4) * 16) ^ swz)); \
        bf16x8 af1 = *(const bf16x8*)(xs + arow + (((kk + 1) * 64 + (lane >> 4) * 16) ^ swz)); \
        bf16x8 af2 = *(const bf16x8*)(xs + arow + (((kk + 2) * 64 + (lane >> 4) * 16) ^ swz)); \
        bf16x8 af3 = *(const bf16x8*)(xs + arow + (((kk + 3) * 64 + (lane >> 4) * 16) ^ swz)); \
        x0 = __builtin_amdgcn_mfma_f32_16x16x32_bf16(af0, wv[i + 0], x0, 0, 0, 0); \
        x1 = __builtin_amdgcn_mfma_f32_16x16x32_bf16(af1, wv[i + 1], x1, 0, 0, 0); \
        x2 = __builtin_amdgcn_mfma_f32_16x16x32_bf16(af2, wv[i + 2], x2, 0, 0, 0); \
        x3 = __builtin_amdgcn_mfma_f32_16x16x32_bf16(af3, wv[i + 3], x3, 0, 0, 0); \
      }                                                                        \
    }                                                                          \
    ZXOUT = (x0 + x1) + (x2 + x3);                                             \
  }

  // prologue: stage x_0, compute zx for t=0
  STAGE_X(0);
  asm volatile("s_waitcnt vmcnt(0)" ::: "memory");
  __builtin_amdgcn_sched_barrier(0);
  __syncthreads();

  f32x4 zx4;
  XW_COMPUTE(zx4);
  f32x4 z4 = {0.f, 0.f, 0.f, 0.f};   // U @ h_{-1} = 0
  unsigned fv = 0;                    // last-seen flag value for this lane

  for (int t = 0; t < SS; ++t) {
    // gate-exchange: z = Uh (z4) + xW (zx4), this wave's gate slice -> zt
    #pragma unroll
    for (int j = 0; j < 4; ++j)
      zt[wave][(lane >> 4) * 4 + j][lane & 15] = z4[j] + zx4[j];
    __syncthreads();

    float zi = zt[0][row][uc] + bi0;
    float zf = zt[1][row][uc] + bi1;
    float zg = zt[2][row][uc] + bi2;
    float zo = zt[3][row][uc] + bi3;
    float ig = 1.f / (1.f + __expf(-zi));
    float fg = 1.f / (1.f + __expf(-zf));
    float gg = 1.f - 2.f / (1.f + __expf(2.f * zg));
    float og = 1.f / (1.f + __expf(-zo));
    c = fg * c + ig * gg;
    float h = og * (1.f - 2.f / (1.f + __expf(2.f * c)));

    if (t == SS - 1) {
      out[((size_t)grow * SS + t) * DD + unit] = h;
      const size_t S0 = (size_t)BB * SS * DD;
      out[S0 + (size_t)grow * DD + unit] = h;                     // ht
      out[S0 + (size_t)BB * DD + (size_t)grow * DD + unit] = c;   // ct
      break;
    }

    // stage x_{t+1} (safe: all xs ds_reads finished before the barrier above)
    STAGE_X(t + 1);

    unsigned short* hn = (t & 1) ? h0 : h1;
    // agent-coherent h store — tid-contiguous, wave writes 128B coalesced
    __hip_atomic_store(hn + hoff, f2bf(h), __ATOMIC_RELAXED, __HIP_MEMORY_SCOPE_AGENT);
    __syncthreads();  // drains gload_lds + h-store (vmcnt(0) before s_barrier)
    if (tid == 0)     // uncontended per-producer flag, monotonic tag
      __hip_atomic_store(myflags + ugrp, (unsigned)(t + 1), __ATOMIC_RELAXED, __HIP_MEMORY_SCOPE_AGENT);
    // deferred: out-store + the ENTIRE xW phase overlap flag propagation
    out[((size_t)grow * SS + t) * DD + unit] = h;
    XW_COMPUTE(zx4);

    // drain W loads + out-store so the counted asm pipeline below is exact
    asm volatile("s_waitcnt vmcnt(0)" ::: "memory");
    __builtin_amdgcn_sched_barrier(0);

    // ---- Uh consumption: r7's proven 4-batch flag-gated pipeline ----
    const unsigned tgt = (unsigned)(t + 1);
    const char* hb = (const char*)((t & 1) ? h0 : h1) + (size_t)rgrp * 32768 + lane * 16;
    const bf16x8* uv = (const bf16x8*)upw;
    f32x4 a0 = {0.f,0.f,0.f,0.f}, a1 = a0, a2 = a0, a3 = a0;
    #pragma unroll
    for (int b = 0; b < 4; ++b) {
      while (((__ballot((int)(fv >= tgt)) >> (16 * b)) & 0xFFFFull) != 0xFFFFull)
        fv = __hip_atomic_load(myflags + lane, __ATOMIC_RELAXED, __HIP_MEMORY_SCOPE_AGENT);
      bf16x8 av0, av1, av2, av3, av4, av5, av6, av7;
      const char* hbb = hb + b * 8192;
      asm volatile("global_load_dwordx4 %0, %1, off sc0 sc1" : "=v"(av0) : "v"(hbb + 0 * 1024) : "memory");
      asm volatile("global_load_dwordx4 %0, %1, off sc0 sc1" : "=v"(av1) : "v"(hbb + 1 * 1024) : "memory");
      asm volatile("global_load_dwordx4 %0, %1, off sc0 sc1" : "=v"(av2) : "v"(hbb + 2 * 1024) : "memory");
      asm volatile("global_load_dwordx4 %0, %1, off sc0 sc1" : "=v"(av3) : "v"(hbb + 3 * 1024) : "memory");
      asm volatile("global_load_dwordx4 %0, %1, off sc0 sc1" : "=v"(av4) : "v"(hbb + 4 * 1024) : "memory");
      asm volatile("global_load_dwordx4 %0, %1, off sc0 sc1" : "=v"(av5) : "v"(hbb + 5 * 1024) : "memory");
      asm volatile("global_load_dwordx4 %0, %1, off sc0 sc1" : "=v"(av6) : "v"(hbb + 6 * 1024) : "memory");
      asm volatile("global_load_dwordx4 %0, %1, off sc0 sc1" : "=v"(av7) : "v"(hbb + 7 * 1024) : "memory");
      asm volatile("s_waitcnt vmcnt(0)" ::: "memory");
      __builtin_amdgcn_sched_barrier(0);
      const int k0 = b * 8;
      a0 = __builtin_amdgcn_mfma_f32_16x16x32_bf16(av0, (k0 + 0 < 30) ? uv[(k0 + 0) * 64 + lane] : ((k0 + 0 == 30) ? u30 : u31), a0, 0, 0, 0);
      a1 = __builtin_amdgcn_mfma_f32_16x16x32_bf16(av1, (k0 + 1 < 30) ? uv[(k0 + 1) * 64 + lane] : ((k0 + 1 == 30) ? u30 : u31), a1, 0, 0, 0);
      a2 = __builtin_amdgcn_mfma_f32_16x16x32_bf16(av2, (k0 + 2 < 30) ? uv[(k0 + 2) * 64 + lane] : ((k0 + 2 == 30) ? u30 : u31), a2, 0, 0, 0);
      a3 = __builtin_amdgcn_mfma_f32_16x16x32_bf16(av3, (k0 + 3 < 30) ? uv[(k0 + 3) * 64 + lane] : ((k0 + 3 == 30) ? u30 : u31), a3, 0, 0, 0);
      a0 = __builtin_amdgcn_mfma_f32_16x16x32_bf16(av4, (k0 + 4 < 30) ? uv[(k0 + 4) * 64 + lane] : ((k0 + 4 == 30) ? u30 : u31), a0, 0, 0, 0);
      a1 = __builtin_amdgcn_mfma_f32_16x16x32_bf16(av5, (k0 + 5 < 30) ? uv[(k0 + 5) * 64 + lane] : ((k0 + 5 == 30) ? u30 : u31), a1, 0, 0, 0);
      a2 = __builtin_amdgcn_mfma_f32_16x16x32_bf16(av6, (k0 + 6 < 30) ? uv[(k0 + 6) * 64 + lane] : ((k0 + 6 == 30) ? u30 : u31), a2, 0, 0, 0);
      a3 = __builtin_amdgcn_mfma_f32_16x16x32_bf16(av7, (k0 + 7 < 30) ? uv[(k0 + 7) * 64 + lane] : ((k0 + 7 == 30) ? u30 : u31), a3, 0, 0, 0);
    }
    z4 = (a0 + a1) + (a2 + a3);
  }
#undef STAGE_X
#undef XW_COMPUTE
}

// ---- round-1 step kernel kept as ws-size fallback ----
template <bool XBF>
__global__ __launch_bounds__(256) void lstm_step(
    const unsigned short* __restrict__ xb, const float* __restrict__ xf,
    const unsigned short* __restrict__ Wt, const unsigned short* __restrict__ Ut,
    const float* __restrict__ bias, unsigned short* __restrict__ hbuf,
    float* __restrict__ cbuf, float* __restrict__ out, int t) {
  __shared__ float ztl[4][16][16];
  const int wg = blockIdx.x;
  const int ugrp = wg >> 2, rgrp = wg & 3;
  const int row0 = rgrp * 16;
  const int ucol0 = ugrp * 16;
  const int wave = threadIdx.x >> 6;
  const int lane = threadIdx.x & 63;
  const int k0 = (lane >> 4) * 8;
  const int gr = row0 + (lane & 15);
  const int cg = wave * DD + ucol0 + (lane & 15);

  const unsigned short* hp = hbuf + (size_t)(t & 1) * BB * DD + (size_t)gr * DD + k0;
  const unsigned short* wp = Wt + (size_t)cg * DD + k0;
  const unsigned short* up = Ut + (size_t)cg * DD + k0;

  f32x4 acc = {0.f, 0.f, 0.f, 0.f};
  if (XBF) {
    const unsigned short* xpp = xb + ((size_t)gr * SS + t) * DD + k0;
    #pragma unroll 8
    for (int kk = 0; kk < DD; kk += 32) {
      bf16x8 a = *(const bf16x8*)(xpp + kk);
      bf16x8 b = *(const bf16x8*)(wp + kk);
      acc = __builtin_amdgcn_mfma_f32_16x16x32_bf16(a, b, acc, 0, 0, 0);
    }
  } else {
    const float* xpp = xf + ((size_t)gr * SS + t) * DD + k0;
    #pragma unroll 4
    for (int kk = 0; kk < DD; kk += 32) {
      float4 v0 = *(const float4*)(xpp + kk);
      float4 v1 = *(const float4*)(xpp + kk + 4);
      bf16x8 a;
      a[0] = (short)f2bf(v0.x); a[1] = (short)f2bf(v0.y);
      a[2] = (short)f2bf(v0.z); a[3] = (short)f2bf(v0.w);
      a[4] = (short)f2bf(v1.x); a[5] = (short)f2bf(v1.y);
      a[6] = (short)f2bf(v1.z); a[7] = (short)f2bf(v1.w);
      bf16x8 b = *(const bf16x8*)(wp + kk);
      acc = __builtin_amdgcn_mfma_f32_16x16x32_bf16(a, b, acc, 0, 0, 0);
    }
  }
  #pragma unroll 8
  for (int kk = 0; kk < DD; kk += 32) {
    bf16x8 a = *(const bf16x8*)(hp + kk);
    bf16x8 b = *(const bf16x8*)(up + kk);
    acc = __builtin_amdgcn_mfma_f32_16x16x32_bf16(a, b, acc, 0, 0, 0);
  }

  float bv = bias[cg];
  #pragma unroll
  for (int j = 0; j < 4; ++j)
    ztl[wave][(lane >> 4) * 4 + j][lane & 15] = acc[j] + bv;
  __syncthreads();

  const int r = threadIdx.x >> 4, uc = threadIdx.x & 15;
  float zi = ztl[0][r][uc], zf = ztl[1][r][uc], zg = ztl[2][r][uc], zo = ztl[3][r][uc];
  float ig = 1.f / (1.f + __expf(-zi));
  float fg = 1.f / (1.f + __expf(-zf));
  float gg = tanhf(zg);
  float og = 1.f / (1.f + __expf(-zo));
  const int gidx = (row0 + r) * DD + ucol0 + uc;
  float c = fg * cbuf[gidx] + ig * gg;
  cbuf[gidx] = c;
  float h = og * tanhf(c);
  hbuf[(size_t)((t & 1) ^ 1) * BB * DD + gidx] = f2bf(h);
  out[((size_t)(row0 + r) * SS + t) * DD + ucol0 + uc] = h;
  if (t == SS - 1) {
    out[(size_t)BB * SS * DD + gidx] = h;
    out[(size_t)BB * SS * DD + BB * DD + gidx] = c;
  }
}

extern "C" void kernel_launch(void* const* d_in, const int* in_sizes, int n_in,
                              void* d_out, int out_size, void* d_ws, size_t ws_size,
                              hipStream_t stream) {
  const float* x = (const float*)d_in[0];
  const float* W = (const float*)d_in[1];
  const float* U = (const float*)d_in[2];
  const float* bias = (const float*)d_in[3];
  float* out = (float*)d_out;
  char* ws = (char*)d_ws;

  // layout: Wt | Ut | h0 | h1 | cbuf | bar | xb | Up | Wp
  const size_t oWt = 0;
  const size_t oUt = oWt + (size_t)G4 * DD * 2;
  const size_t oH0 = oUt + (size_t)G4 * DD * 2;
  const size_t oH1 = oH0 + (size_t)BB * DD * 2;
  const size_t oC  = oH1 + (size_t)BB * DD * 2;
  const size_t oBar = oC + (size_t)BB * DD * 4;
  const size_t oXb = oBar + 4096;
  const size_t oUp = oXb + (size_t)BB * SS * DD * 2;
  const size_t oWp = oUp + (size_t)G4 * DD * 2;
  const size_t needFused = oWp + (size_t)G4 * DD * 2;
  const size_t needR1x = oUp;

  unsigned short* Wt = (unsigned short*)(ws + oWt);
  unsigned short* Ut = (unsigned short*)(ws + oUt);
  unsigned short* h0 = (unsigned short*)(ws + oH0);
  unsigned short* h1 = (unsigned short*)(ws + oH1);
  float* cbuf = (float*)(ws + oC);
  unsigned int* bar = (unsigned int*)(ws + oBar);
  unsigned short* xb = (unsigned short*)(ws + oXb);
  unsigned short* Up = (unsigned short*)(ws + oUp);
  unsigned short* Wp = (unsigned short*)(ws + oWp);

  if (ws_size >= needFused) {
    hipFuncSetAttribute((const void*)lstm_persist,
                        hipFuncAttributeMaxDynamicSharedMemorySize, 159744);
    hipMemsetAsync(h0, 0, (size_t)BB * DD * 2, stream);
    hipMemsetAsync(bar, 0, 4096, stream);
    cvt_transpose<<<dim3(32, 128, 2), 256, 0, stream>>>(W, U, Wt, Ut);
    pack_u<<<2048, 256, 0, stream>>>(Ut, Up);
    pack_u<<<2048, 256, 0, stream>>>(Wt, Wp);
    cvt_x<<<2048, 256, 0, stream>>>(x, xb, BB * SS * DD / 8);
    lstm_persist<<<256, 256, 159744, stream>>>(xb, Up, Wp, h0, h1, bar, bias, out);
  } else {
    unsigned short* hbuf = h0;  // h0|h1 contiguous
    const bool xbf = ws_size >= needR1x;
    hipMemsetAsync(hbuf, 0, (size_t)2 * BB * DD * 2 + (size_t)BB * DD * 4, stream);
    cvt_transpose<<<dim3(32, 128, 2), 256, 0, stream>>>(W, U, Wt, Ut);
    if (xbf) cvt_x<<<2048, 256, 0, stream>>>(x, xb, BB * SS * DD / 8);
    for (int t = 0; t < SS; ++t) {
      if (xbf)
        lstm_step<true><<<256, 256, 0, stream>>>(xb, nullptr, Wt, Ut, bias, hbuf, cbuf, out, t);
      else
        lstm_step<false><<<256, 256, 0, stream>>>(nullptr, x, Wt, Ut, bias, hbuf, cbuf, out, t);
    }
  }
}

// Round 11
// 2463.762 us; speedup vs baseline: 1.1003x; 1.1003x over previous
//
#include <hip/hip_runtime.h>
#include <hip/hip_bf16.h>
#include <cstdint>
#include <cstddef>

#define BB 64
#define SS 512
#define DD 1024
#define G4 4096  // 4*units

typedef __attribute__((ext_vector_type(8))) short bf16x8;
typedef __attribute__((ext_vector_type(8))) unsigned short u16x8;
typedef __attribute__((ext_vector_type(4))) float f32x4;

static __device__ __forceinline__ unsigned short f2bf(float f) {
  union { float f; uint32_t u; } v; v.f = f;
  uint32_t u = v.u;
  return (unsigned short)((u + 0x7FFFu + ((u >> 16) & 1u)) >> 16);  // RTNE
}
static __device__ __forceinline__ float bf2f(unsigned short s) {
  union { uint32_t u; float f; } v; v.u = ((uint32_t)s) << 16; return v.f;
}

typedef __attribute__((address_space(1))) const unsigned int kGlbU32;
typedef __attribute__((address_space(3))) unsigned int kLdsU32;
static __device__ __forceinline__ void gload_lds16(const void* g, void* l) {
  __builtin_amdgcn_global_load_lds((kGlbU32*)g, (kLdsU32*)l, 16, 0, 0);
}

// ---- convert x (f32 -> bf16), vectorized ----
__global__ void cvt_x(const float* __restrict__ in, unsigned short* __restrict__ out, int n8) {
  for (int i = blockIdx.x * blockDim.x + threadIdx.x; i < n8; i += gridDim.x * blockDim.x) {
    const float4* pp = (const float4*)(in + (size_t)i * 8);
    float4 a = pp[0], b2 = pp[1];
    u16x8 o;
    o[0] = f2bf(a.x);  o[1] = f2bf(a.y);  o[2] = f2bf(a.z);  o[3] = f2bf(a.w);
    o[4] = f2bf(b2.x); o[5] = f2bf(b2.y); o[6] = f2bf(b2.z); o[7] = f2bf(b2.w);
    *(u16x8*)(out + (size_t)i * 8) = o;
  }
}

// ---- transpose-convert W,U: in[k][c] f32 -> out[c][k] bf16 ----
__global__ __launch_bounds__(256) void cvt_transpose(
    const float* __restrict__ Win, const float* __restrict__ Uin,
    unsigned short* __restrict__ Wt, unsigned short* __restrict__ Ut) {
  __shared__ float tile[32][33];
  const float* in = blockIdx.z ? Uin : Win;
  unsigned short* out = blockIdx.z ? Ut : Wt;
  int k0 = blockIdx.x * 32;
  int c0 = blockIdx.y * 32;
  int tc = threadIdx.x & 31, tr = threadIdx.x >> 5;
  #pragma unroll
  for (int j = 0; j < 32; j += 8)
    tile[tr + j][tc] = in[(size_t)(k0 + tr + j) * G4 + (c0 + tc)];
  __syncthreads();
  #pragma unroll
  for (int j = 0; j < 32; j += 8)
    out[(size_t)(c0 + tr + j) * DD + (k0 + tc)] = f2bf(tile[tc][tr + j]);
}

// ---- pack Ut[col][k] into MFMA B-fragment order ----
__global__ __launch_bounds__(256) void pack_u(const unsigned short* __restrict__ Ut,
                                              unsigned short* __restrict__ Up) {
  int tid = blockIdx.x * 256 + threadIdx.x;  // 64*4*32*64 = 524288 total
  int l = tid & 63;
  int kk = (tid >> 6) & 31;
  int g = (tid >> 11) & 3;
  int u = tid >> 13;
  int col = g * DD + u * 16 + (l & 15);
  int k = kk * 32 + (l >> 4) * 8;
  bf16x8 v = *(const bf16x8*)(Ut + (size_t)col * DD + k);
  *(bf16x8*)(Up + (size_t)tid * 8) = v;
}

// ---- xproj GEMM -> packed layout [t][rgrp][ugrp][r*16+uc][g] bf16, bias folded ----
__global__ __launch_bounds__(256) void gemm_xproj(
    const unsigned short* __restrict__ xb,   // bf16 [32768][1024]
    const unsigned short* __restrict__ Wt,   // bf16 [4096][1024]
    const float* __restrict__ bias,
    unsigned short* __restrict__ xproj) {
  __shared__ unsigned short As[128 * 64], Bs[128 * 64];
  const int tid = threadIdx.x;
  const int wave = tid >> 6, lane = tid & 63;
  const int wr = wave >> 1, wc = wave & 1;
  const int m0 = blockIdx.x * 128, n0 = blockIdx.y * 128;

  const int srow = tid >> 1, shalf = tid & 1;
  const unsigned short* ga = xb + (size_t)(m0 + srow) * DD + shalf * 32;
  const unsigned short* gb = Wt + (size_t)(n0 + srow) * DD + shalf * 32;

  bf16x8 ra[4], rb[4];
  #pragma unroll
  for (int c = 0; c < 4; ++c) {
    ra[c] = *(const bf16x8*)(ga + c * 8);
    rb[c] = *(const bf16x8*)(gb + c * 8);
  }

  f32x4 acc[4][4];
  #pragma unroll
  for (int m = 0; m < 4; ++m)
    #pragma unroll
    for (int n = 0; n < 4; ++n) acc[m][n] = (f32x4){0.f, 0.f, 0.f, 0.f};

  char* asb = (char*)As;
  char* bsb = (char*)Bs;

  for (int kt = 0; kt < DD / 64; ++kt) {
    __syncthreads();
    #pragma unroll
    for (int c = 0; c < 4; ++c) {
      int wb = srow * 128 + ((shalf * 64 + c * 16) ^ ((srow & 7) << 4));
      *(bf16x8*)(asb + wb) = ra[c];
      *(bf16x8*)(bsb + wb) = rb[c];
    }
    __syncthreads();
    if (kt + 1 < DD / 64) {
      #pragma unroll
      for (int c = 0; c < 4; ++c) {
        ra[c] = *(const bf16x8*)(ga + (kt + 1) * 64 + c * 8);
        rb[c] = *(const bf16x8*)(gb + (kt + 1) * 64 + c * 8);
      }
    }
    #pragma unroll
    for (int kh = 0; kh < 2; ++kh) {
      bf16x8 af[4], bfr[4];
      const int kb = kh * 64 + (lane >> 4) * 16;
      #pragma unroll
      for (int m = 0; m < 4; ++m) {
        int row = wr * 64 + m * 16 + (lane & 15);
        af[m] = *(const bf16x8*)(asb + row * 128 + (kb ^ ((row & 7) << 4)));
        int coln = wc * 64 + m * 16 + (lane & 15);
        bfr[m] = *(const bf16x8*)(bsb + coln * 128 + (kb ^ ((coln & 7) << 4)));
      }
      #pragma unroll
      for (int m = 0; m < 4; ++m)
        #pragma unroll
        for (int n = 0; n < 4; ++n)
          acc[m][n] = __builtin_amdgcn_mfma_f32_16x16x32_bf16(af[m], bfr[n], acc[m][n], 0, 0, 0);
    }
  }

  #pragma unroll
  for (int n = 0; n < 4; ++n) {
    int col = n0 + wc * 64 + n * 16 + (lane & 15);
    int g = col >> 10, unit = col & 1023;
    int ugrp2 = unit >> 4, uc2 = unit & 15;
    float bv = bias[col];
    #pragma unroll
    for (int m = 0; m < 4; ++m) {
      #pragma unroll
      for (int j = 0; j < 4; ++j) {
        int mrow = m0 + wr * 64 + m * 16 + (lane >> 4) * 4 + j;
        int b = mrow >> 9, t2 = mrow & 511;
        size_t idx = ((((size_t)t2 * 4 + (b >> 4)) * 64 + ugrp2) * 256 + (b & 15) * 16 + uc2) * 4 + g;
        xproj[idx] = f2bf(acc[m][n][j] + bv);
      }
    }
  }
}

// ---- persistent recurrence kernel: 256 wgs (1/CU), U resident in LDS ----
// (round-7 configuration — best measured: total 2461 us)
// Coherent h handoff; per-producer flags; ALL waves poll independently;
// A-fragments loaded DIRECTLY from the coherent h buffer in 4 batches of 8.
// Dynamic LDS (124 KB): [0,122880) Up: 4 waves x 30 frags; [122880,+4K) zt.
__global__ __launch_bounds__(256, 1) void lstm_persist(
    const unsigned short* __restrict__ xproj,  // packed, bias folded
    const unsigned short* __restrict__ Up,     // packed B-frags
    unsigned short* __restrict__ h0,           // packed A-frags [4][32][64][8]
    unsigned short* __restrict__ h1,
    unsigned int* __restrict__ bar,            // flags[4][64] dwords, zeroed
    float* __restrict__ out) {
  extern __shared__ char smem[];
  const int bid = blockIdx.x;
  const int rgrp = (bid & 7) >> 1;             // XCD-pair-friendly mapping
  const int ugrp = (bid >> 3) * 2 + (bid & 1);
  const int tid = threadIdx.x;
  const int wave = tid >> 6, lane = tid & 63;
  const int r = tid >> 4, uc = tid & 15;
  const int row = rgrp * 16 + r, unit = ugrp * 16 + uc;

  char* upw = smem + wave * 30720;             // this wave's 30 U-frags
  float (*zt)[16][16] = (float (*)[16][16])(smem + 122880);

  // one-time: stage this wave's U fragments (30 to LDS, 2 to regs)
  const char* ug = (const char*)Up + (size_t)(ugrp * 4 + wave) * 32768;
  #pragma unroll
  for (int kk = 0; kk < 30; ++kk)
    gload_lds16(ug + kk * 1024 + lane * 16, upw + kk * 1024 + lane * 16);
  bf16x8 u30 = *(const bf16x8*)(ug + 30 * 1024 + lane * 16);
  bf16x8 u31 = *(const bf16x8*)(ug + 31 * 1024 + lane * 16);

  const unsigned short* xp = xproj + (((size_t)rgrp * 64 + ugrp) * 256 + tid) * 4;
  const int hnidx = ((rgrp * 32 + (unit >> 5)) * 64 + ((unit >> 3) & 3) * 16 + r) * 8 + (unit & 7);
  unsigned int* myflags = bar + rgrp * 64;     // 64 dwords, one per producer
  float c = 0.f;
  ushort4 xv = *(const ushort4*)xp;  // t=0 pre-activations

  asm volatile("s_waitcnt vmcnt(0)" ::: "memory");
  __builtin_amdgcn_sched_barrier(0);
  __syncthreads();

  const bf16x8* uv = (const bf16x8*)upw;
  f32x4 z4 = {0.f, 0.f, 0.f, 0.f};  // U @ h_{-1} = 0
  unsigned fv = 0;                   // last-seen flag value for this lane

  for (int t = 0; t < SS; ++t) {
    // gate-exchange: z4 (this wave's gate slice) -> zt
    #pragma unroll
    for (int j = 0; j < 4; ++j)
      zt[wave][(lane >> 4) * 4 + j][lane & 15] = z4[j];
    __syncthreads();

    float zi = zt[0][r][uc] + bf2f(xv.x);
    float zf = zt[1][r][uc] + bf2f(xv.y);
    float zg = zt[2][r][uc] + bf2f(xv.z);
    float zo = zt[3][r][uc] + bf2f(xv.w);
    float ig = 1.f / (1.f + __expf(-zi));
    float fg = 1.f / (1.f + __expf(-zf));
    float gg = 1.f - 2.f / (1.f + __expf(2.f * zg));
    float og = 1.f / (1.f + __expf(-zo));
    c = fg * c + ig * gg;
    float h = og * (1.f - 2.f / (1.f + __expf(2.f * c)));

    if (t == SS - 1) {
      out[((size_t)row * SS + t) * DD + unit] = h;
      const size_t S0 = (size_t)BB * SS * DD;
      out[S0 + (size_t)row * DD + unit] = h;                     // ht
      out[S0 + (size_t)BB * DD + (size_t)row * DD + unit] = c;   // ct
      break;
    }

    unsigned short* hn = (t & 1) ? h0 : h1;
    // agent-coherent h store (write-through; no dirty L2 line)
    __hip_atomic_store(hn + hnidx, f2bf(h), __ATOMIC_RELAXED, __HIP_MEMORY_SCOPE_AGENT);
    __syncthreads();  // per-thread vmcnt drain before barrier => release pattern
    if (tid == 0)     // uncontended per-producer flag, monotonic tag
      __hip_atomic_store(myflags + ugrp, (unsigned)(t + 1), __ATOMIC_RELAXED, __HIP_MEMORY_SCOPE_AGENT);
    // deferred work overlaps flag propagation:
    out[((size_t)row * SS + t) * DD + unit] = h;
    xv = *(const ushort4*)(xp + (size_t)(t + 1) * 262144);

    // ---- incremental pipelined consumption of h_t ----
    const char* hb = (const char*)((t & 1) ? h0 : h1) + rgrp * 32768 + lane * 16;
    const unsigned tgt = (unsigned)(t + 1);
    f32x4 a0 = {0.f,0.f,0.f,0.f}, a1 = a0, a2 = a0, a3 = a0;
    #pragma unroll
    for (int b = 0; b < 4; ++b) {
      // wait until producers [16b, 16b+16) have stored (ballot over 64 flags)
      while ((( __ballot((int)(fv >= tgt)) >> (16 * b)) & 0xFFFFull) != 0xFFFFull)
        fv = __hip_atomic_load(myflags + lane, __ATOMIC_RELAXED, __HIP_MEMORY_SCOPE_AGENT);
      // issue 8 independent coherent A-fragment loads
      bf16x8 av0, av1, av2, av3, av4, av5, av6, av7;
      const char* hbb = hb + b * 8192;
      asm volatile("global_load_dwordx4 %0, %1, off sc0 sc1" : "=v"(av0) : "v"(hbb + 0 * 1024) : "memory");
      asm volatile("global_load_dwordx4 %0, %1, off sc0 sc1" : "=v"(av1) : "v"(hbb + 1 * 1024) : "memory");
      asm volatile("global_load_dwordx4 %0, %1, off sc0 sc1" : "=v"(av2) : "v"(hbb + 2 * 1024) : "memory");
      asm volatile("global_load_dwordx4 %0, %1, off sc0 sc1" : "=v"(av3) : "v"(hbb + 3 * 1024) : "memory");
      asm volatile("global_load_dwordx4 %0, %1, off sc0 sc1" : "=v"(av4) : "v"(hbb + 4 * 1024) : "memory");
      asm volatile("global_load_dwordx4 %0, %1, off sc0 sc1" : "=v"(av5) : "v"(hbb + 5 * 1024) : "memory");
      asm volatile("global_load_dwordx4 %0, %1, off sc0 sc1" : "=v"(av6) : "v"(hbb + 6 * 1024) : "memory");
      asm volatile("global_load_dwordx4 %0, %1, off sc0 sc1" : "=v"(av7) : "v"(hbb + 7 * 1024) : "memory");
      asm volatile("s_waitcnt vmcnt(0)" ::: "memory");
      __builtin_amdgcn_sched_barrier(0);
      const int k0 = b * 8;
      a0 = __builtin_amdgcn_mfma_f32_16x16x32_bf16(av0, (k0 + 0 < 30) ? uv[(k0 + 0) * 64 + lane] : ((k0 + 0 == 30) ? u30 : u31), a0, 0, 0, 0);
      a1 = __builtin_amdgcn_mfma_f32_16x16x32_bf16(av1, (k0 + 1 < 30) ? uv[(k0 + 1) * 64 + lane] : ((k0 + 1 == 30) ? u30 : u31), a1, 0, 0, 0);
      a2 = __builtin_amdgcn_mfma_f32_16x16x32_bf16(av2, (k0 + 2 < 30) ? uv[(k0 + 2) * 64 + lane] : ((k0 + 2 == 30) ? u30 : u31), a2, 0, 0, 0);
      a3 = __builtin_amdgcn_mfma_f32_16x16x32_bf16(av3, (k0 + 3 < 30) ? uv[(k0 + 3) * 64 + lane] : ((k0 + 3 == 30) ? u30 : u31), a3, 0, 0, 0);
      a0 = __builtin_amdgcn_mfma_f32_16x16x32_bf16(av4, (k0 + 4 < 30) ? uv[(k0 + 4) * 64 + lane] : ((k0 + 4 == 30) ? u30 : u31), a0, 0, 0, 0);
      a1 = __builtin_amdgcn_mfma_f32_16x16x32_bf16(av5, (k0 + 5 < 30) ? uv[(k0 + 5) * 64 + lane] : ((k0 + 5 == 30) ? u30 : u31), a1, 0, 0, 0);
      a2 = __builtin_amdgcn_mfma_f32_16x16x32_bf16(av6, (k0 + 6 < 30) ? uv[(k0 + 6) * 64 + lane] : ((k0 + 6 == 30) ? u30 : u31), a2, 0, 0, 0);
      a3 = __builtin_amdgcn_mfma_f32_16x16x32_bf16(av7, (k0 + 7 < 30) ? uv[(k0 + 7) * 64 + lane] : ((k0 + 7 == 30) ? u30 : u31), a3, 0, 0, 0);
    }
    z4 = (a0 + a1) + (a2 + a3);
  }
}

// ---- round-1 step kernel kept as ws-size fallback ----
template <bool XBF>
__global__ __launch_bounds__(256) void lstm_step(
    const unsigned short* __restrict__ xb, const float* __restrict__ xf,
    const unsigned short* __restrict__ Wt, const unsigned short* __restrict__ Ut,
    const float* __restrict__ bias, unsigned short* __restrict__ hbuf,
    float* __restrict__ cbuf, float* __restrict__ out, int t) {
  __shared__ float ztl[4][16][16];
  const int wg = blockIdx.x;
  const int ugrp = wg >> 2, rgrp = wg & 3;
  const int row0 = rgrp * 16;
  const int ucol0 = ugrp * 16;
  const int wave = threadIdx.x >> 6;
  const int lane = threadIdx.x & 63;
  const int k0 = (lane >> 4) * 8;
  const int gr = row0 + (lane & 15);
  const int cg = wave * DD + ucol0 + (lane & 15);

  const unsigned short* hp = hbuf + (size_t)(t & 1) * BB * DD + (size_t)gr * DD + k0;
  const unsigned short* wp = Wt + (size_t)cg * DD + k0;
  const unsigned short* up = Ut + (size_t)cg * DD + k0;

  f32x4 acc = {0.f, 0.f, 0.f, 0.f};
  if (XBF) {
    const unsigned short* xpp = xb + ((size_t)gr * SS + t) * DD + k0;
    #pragma unroll 8
    for (int kk = 0; kk < DD; kk += 32) {
      bf16x8 a = *(const bf16x8*)(xpp + kk);
      bf16x8 b = *(const bf16x8*)(wp + kk);
      acc = __builtin_amdgcn_mfma_f32_16x16x32_bf16(a, b, acc, 0, 0, 0);
    }
  } else {
    const float* xpp = xf + ((size_t)gr * SS + t) * DD + k0;
    #pragma unroll 4
    for (int kk = 0; kk < DD; kk += 32) {
      float4 v0 = *(const float4*)(xpp + kk);
      float4 v1 = *(const float4*)(xpp + kk + 4);
      bf16x8 a;
      a[0] = (short)f2bf(v0.x); a[1] = (short)f2bf(v0.y);
      a[2] = (short)f2bf(v0.z); a[3] = (short)f2bf(v0.w);
      a[4] = (short)f2bf(v1.x); a[5] = (short)f2bf(v1.y);
      a[6] = (short)f2bf(v1.z); a[7] = (short)f2bf(v1.w);
      bf16x8 b = *(const bf16x8*)(wp + kk);
      acc = __builtin_amdgcn_mfma_f32_16x16x32_bf16(a, b, acc, 0, 0, 0);
    }
  }
  #pragma unroll 8
  for (int kk = 0; kk < DD; kk += 32) {
    bf16x8 a = *(const bf16x8*)(hp + kk);
    bf16x8 b = *(const bf16x8*)(up + kk);
    acc = __builtin_amdgcn_mfma_f32_16x16x32_bf16(a, b, acc, 0, 0, 0);
  }

  float bv = bias[cg];
  #pragma unroll
  for (int j = 0; j < 4; ++j)
    ztl[wave][(lane >> 4) * 4 + j][lane & 15] = acc[j] + bv;
  __syncthreads();

  const int r = threadIdx.x >> 4, uc = threadIdx.x & 15;
  float zi = ztl[0][r][uc], zf = ztl[1][r][uc], zg = ztl[2][r][uc], zo = ztl[3][r][uc];
  float ig = 1.f / (1.f + __expf(-zi));
  float fg = 1.f / (1.f + __expf(-zf));
  float gg = tanhf(zg);
  float og = 1.f / (1.f + __expf(-zo));
  const int gidx = (row0 + r) * DD + ucol0 + uc;
  float c = fg * cbuf[gidx] + ig * gg;
  cbuf[gidx] = c;
  float h = og * tanhf(c);
  hbuf[(size_t)((t & 1) ^ 1) * BB * DD + gidx] = f2bf(h);
  out[((size_t)(row0 + r) * SS + t) * DD + ucol0 + uc] = h;
  if (t == SS - 1) {
    out[(size_t)BB * SS * DD + gidx] = h;
    out[(size_t)BB * SS * DD + BB * DD + gidx] = c;
  }
}

extern "C" void kernel_launch(void* const* d_in, const int* in_sizes, int n_in,
                              void* d_out, int out_size, void* d_ws, size_t ws_size,
                              hipStream_t stream) {
  const float* x = (const float*)d_in[0];
  const float* W = (const float*)d_in[1];
  const float* U = (const float*)d_in[2];
  const float* bias = (const float*)d_in[3];
  float* out = (float*)d_out;
  char* ws = (char*)d_ws;

  // layout: Wt | Ut | h0 | h1 | cbuf | bar | xb | Up | xproj
  const size_t oWt = 0;
  const size_t oUt = oWt + (size_t)G4 * DD * 2;
  const size_t oH0 = oUt + (size_t)G4 * DD * 2;
  const size_t oH1 = oH0 + (size_t)BB * DD * 2;
  const size_t oC  = oH1 + (size_t)BB * DD * 2;
  const size_t oBar = oC + (size_t)BB * DD * 4;
  const size_t oXb = oBar + 4096;
  const size_t oUp = oXb + (size_t)BB * SS * DD * 2;
  const size_t oXp = oUp + (size_t)G4 * DD * 2;
  const size_t needPersist = oXp + (size_t)SS * BB * G4 * 2;
  const size_t needR1x = oUp;

  unsigned short* Wt = (unsigned short*)(ws + oWt);
  unsigned short* Ut = (unsigned short*)(ws + oUt);
  unsigned short* h0 = (unsigned short*)(ws + oH0);
  unsigned short* h1 = (unsigned short*)(ws + oH1);
  float* cbuf = (float*)(ws + oC);
  unsigned int* bar = (unsigned int*)(ws + oBar);
  unsigned short* xb = (unsigned short*)(ws + oXb);
  unsigned short* Up = (unsigned short*)(ws + oUp);
  unsigned short* xproj = (unsigned short*)(ws + oXp);

  if (ws_size >= needPersist) {
    hipFuncSetAttribute((const void*)lstm_persist,
                        hipFuncAttributeMaxDynamicSharedMemorySize, 126976);
    hipMemsetAsync(h0, 0, (size_t)BB * DD * 2, stream);
    hipMemsetAsync(bar, 0, 4096, stream);
    cvt_transpose<<<dim3(32, 128, 2), 256, 0, stream>>>(W, U, Wt, Ut);
    pack_u<<<2048, 256, 0, stream>>>(Ut, Up);
    cvt_x<<<2048, 256, 0, stream>>>(x, xb, BB * SS * DD / 8);
    gemm_xproj<<<dim3(256, 32), 256, 0, stream>>>(xb, Wt, bias, xproj);
    lstm_persist<<<256, 256, 126976, stream>>>(xproj, Up, h0, h1, bar, out);
  } else {
    unsigned short* hbuf = h0;  // h0|h1 contiguous
    const bool xbf = ws_size >= needR1x;
    hipMemsetAsync(hbuf, 0, (size_t)2 * BB * DD * 2 + (size_t)BB * DD * 4, stream);
    cvt_transpose<<<dim3(32, 128, 2), 256, 0, stream>>>(W, U, Wt, Ut);
    if (xbf) cvt_x<<<2048, 256, 0, stream>>>(x, xb, BB * SS * DD / 8);
    for (int t = 0; t < SS; ++t) {
      if (xbf)
        lstm_step<true><<<256, 256, 0, stream>>>(xb, nullptr, Wt, Ut, bias, hbuf, cbuf, out, t);
      else
        lstm_step<false><<<256, 256, 0, stream>>>(nullptr, x, Wt, Ut, bias, hbuf, cbuf, out, t);
    }
  }
}

// Round 12
// 2325.088 us; speedup vs baseline: 1.1659x; 1.0596x over previous
//
#include <hip/hip_runtime.h>
#include <hip/hip_bf16.h>
#include <cstdint>
#include <cstddef>

#define BB 64
#define SS 512
#define DD 1024
#define G4 4096  // 4*units

typedef __attribute__((ext_vector_type(8))) short bf16x8;
typedef __attribute__((ext_vector_type(8))) unsigned short u16x8;
typedef __attribute__((ext_vector_type(4))) float f32x4;

static __device__ __forceinline__ unsigned short f2bf(float f) {
  union { float f; uint32_t u; } v; v.f = f;
  uint32_t u = v.u;
  return (unsigned short)((u + 0x7FFFu + ((u >> 16) & 1u)) >> 16);  // RTNE
}
static __device__ __forceinline__ float bf2f(unsigned short s) {
  union { uint32_t u; float f; } v; v.u = ((uint32_t)s) << 16; return v.f;
}

typedef __attribute__((address_space(1))) const unsigned int kGlbU32;
typedef __attribute__((address_space(3))) unsigned int kLdsU32;
static __device__ __forceinline__ void gload_lds16(const void* g, void* l) {
  __builtin_amdgcn_global_load_lds((kGlbU32*)g, (kLdsU32*)l, 16, 0, 0);
}

// ---- convert x (f32 -> bf16), vectorized ----
__global__ void cvt_x(const float* __restrict__ in, unsigned short* __restrict__ out, int n8) {
  for (int i = blockIdx.x * blockDim.x + threadIdx.x; i < n8; i += gridDim.x * blockDim.x) {
    const float4* pp = (const float4*)(in + (size_t)i * 8);
    float4 a = pp[0], b2 = pp[1];
    u16x8 o;
    o[0] = f2bf(a.x);  o[1] = f2bf(a.y);  o[2] = f2bf(a.z);  o[3] = f2bf(a.w);
    o[4] = f2bf(b2.x); o[5] = f2bf(b2.y); o[6] = f2bf(b2.z); o[7] = f2bf(b2.w);
    *(u16x8*)(out + (size_t)i * 8) = o;
  }
}

// ---- transpose-convert W,U: in[k][c] f32 -> out[c][k] bf16 ----
__global__ __launch_bounds__(256) void cvt_transpose(
    const float* __restrict__ Win, const float* __restrict__ Uin,
    unsigned short* __restrict__ Wt, unsigned short* __restrict__ Ut) {
  __shared__ float tile[32][33];
  const float* in = blockIdx.z ? Uin : Win;
  unsigned short* out = blockIdx.z ? Ut : Wt;
  int k0 = blockIdx.x * 32;
  int c0 = blockIdx.y * 32;
  int tc = threadIdx.x & 31, tr = threadIdx.x >> 5;
  #pragma unroll
  for (int j = 0; j < 32; j += 8)
    tile[tr + j][tc] = in[(size_t)(k0 + tr + j) * G4 + (c0 + tc)];
  __syncthreads();
  #pragma unroll
  for (int j = 0; j < 32; j += 8)
    out[(size_t)(c0 + tr + j) * DD + (k0 + tc)] = f2bf(tile[tc][tr + j]);
}

// ---- pack Ut[col][k] into MFMA B-fragment order ----
__global__ __launch_bounds__(256) void pack_u(const unsigned short* __restrict__ Ut,
                                              unsigned short* __restrict__ Up) {
  int tid = blockIdx.x * 256 + threadIdx.x;  // 64*4*32*64 = 524288 total
  int l = tid & 63;
  int kk = (tid >> 6) & 31;
  int g = (tid >> 11) & 3;
  int u = tid >> 13;
  int col = g * DD + u * 16 + (l & 15);
  int k = kk * 32 + (l >> 4) * 8;
  bf16x8 v = *(const bf16x8*)(Ut + (size_t)col * DD + k);
  *(bf16x8*)(Up + (size_t)tid * 8) = v;
}

// ---- xproj GEMM: m97-style global_load_lds staging, g-outermost packed out ----
// xproj layout: [g][t][rgrp][ugrp][(b&15)*16 + uc] bf16, bias folded.
__global__ __launch_bounds__(256) void gemm_xproj(
    const unsigned short* __restrict__ xb,   // bf16 [32768][1024]
    const unsigned short* __restrict__ Wt,   // bf16 [4096][1024]
    const float* __restrict__ bias,
    unsigned short* __restrict__ xproj) {
  __shared__ unsigned short As[128 * 64], Bs[128 * 64];  // 16 KB each
  const int tid = threadIdx.x;
  const int wave = tid >> 6, lane = tid & 63;
  const int wr = wave >> 1, wc = wave & 1;
  const int m0 = blockIdx.x * 128, n0 = blockIdx.y * 128;

  char* asb = (char*)As;
  char* bsb = (char*)Bs;

  // staging geometry (rule #21: linear LDS dest + pre-swizzled global source):
  // chunk c covers LDS [c*1024,(c+1)*1024); lane l writes c*1024 + l*16
  //   = (row = c*8 + (l>>3)) * 128 + (l&7)*16
  // want LDS[row*128 + j*16] = global[row][(j ^ (row&7))*16], row&7 = l>>3
  //   => source k-byte = ((l&7) ^ (l>>3)) * 16
  const int srw = lane >> 3;                       // row within chunk stripe
  const int skb = (((lane & 7) ^ srw) << 4);       // pre-swizzled source k-byte

  f32x4 acc[4][4];
  #pragma unroll
  for (int m = 0; m < 4; ++m)
    #pragma unroll
    for (int n = 0; n < 4; ++n) acc[m][n] = (f32x4){0.f, 0.f, 0.f, 0.f};

  for (int kt = 0; kt < DD / 64; ++kt) {
    __syncthreads();  // previous tile's ds_reads complete before overwrite
    #pragma unroll
    for (int q = 0; q < 4; ++q) {
      const int c = wave * 4 + q;                  // chunk 0..15
      gload_lds16((const char*)xb + (size_t)(m0 + c * 8 + srw) * 2048 + kt * 128 + skb,
                  asb + c * 1024 + lane * 16);
      gload_lds16((const char*)Wt + (size_t)(n0 + c * 8 + srw) * 2048 + kt * 128 + skb,
                  bsb + c * 1024 + lane * 16);
    }
    asm volatile("s_waitcnt vmcnt(0)" ::: "memory");
    __builtin_amdgcn_sched_barrier(0);
    __syncthreads();

    #pragma unroll
    for (int kh = 0; kh < 2; ++kh) {
      bf16x8 af[4], bfr[4];
      const int kb = kh * 64 + (lane >> 4) * 16;
      #pragma unroll
      for (int m = 0; m < 4; ++m) {
        int row = wr * 64 + m * 16 + (lane & 15);
        af[m] = *(const bf16x8*)(asb + row * 128 + (kb ^ ((row & 7) << 4)));
        int coln = wc * 64 + m * 16 + (lane & 15);
        bfr[m] = *(const bf16x8*)(bsb + coln * 128 + (kb ^ ((coln & 7) << 4)));
      }
      #pragma unroll
      for (int m = 0; m < 4; ++m)
        #pragma unroll
        for (int n = 0; n < 4; ++n)
          acc[m][n] = __builtin_amdgcn_mfma_f32_16x16x32_bf16(af[m], bfr[n], acc[m][n], 0, 0, 0);
    }
  }

  // C-write: g-outermost packed layout; 16 lanes -> 32B contiguous
  #pragma unroll
  for (int n = 0; n < 4; ++n) {
    int col = n0 + wc * 64 + n * 16 + (lane & 15);
    int g = col >> 10, unit = col & 1023;
    int ugrp2 = unit >> 4, uc2 = unit & 15;
    float bv = bias[col];
    #pragma unroll
    for (int m = 0; m < 4; ++m) {
      #pragma unroll
      for (int j = 0; j < 4; ++j) {
        int mrow = m0 + wr * 64 + m * 16 + (lane >> 4) * 4 + j;
        int b = mrow >> 9, t2 = mrow & 511;
        size_t idx = ((((size_t)g * SS + t2) * 4 + (b >> 4)) * 64 + ugrp2) * 256
                     + (b & 15) * 16 + uc2;
        xproj[idx] = f2bf(acc[m][n][j] + bv);
      }
    }
  }
}

// ---- persistent recurrence kernel: 256 wgs (1/CU), U resident in LDS ----
// (round-7/11 configuration — persist at its measured latency floor)
// Coherent h handoff; per-producer flags; ALL waves poll independently;
// A-fragments loaded DIRECTLY from the coherent h buffer in 4 batches of 8.
// xproj now g-outermost: 4 scalar gate loads, issued in the spin shadow.
// Dynamic LDS (124 KB): [0,122880) Up: 4 waves x 30 frags; [122880,+4K) zt.
__global__ __launch_bounds__(256, 1) void lstm_persist(
    const unsigned short* __restrict__ xproj,  // packed [g][t][rgrp][ugrp][256]
    const unsigned short* __restrict__ Up,     // packed B-frags
    unsigned short* __restrict__ h0,           // packed A-frags [4][32][64][8]
    unsigned short* __restrict__ h1,
    unsigned int* __restrict__ bar,            // flags[4][64] dwords, zeroed
    float* __restrict__ out) {
  extern __shared__ char smem[];
  const int bid = blockIdx.x;
  const int rgrp = (bid & 7) >> 1;             // XCD-pair-friendly mapping
  const int ugrp = (bid >> 3) * 2 + (bid & 1);
  const int tid = threadIdx.x;
  const int wave = tid >> 6, lane = tid & 63;
  const int r = tid >> 4, uc = tid & 15;
  const int row = rgrp * 16 + r, unit = ugrp * 16 + uc;

  char* upw = smem + wave * 30720;             // this wave's 30 U-frags
  float (*zt)[16][16] = (float (*)[16][16])(smem + 122880);

  // one-time: stage this wave's U fragments (30 to LDS, 2 to regs)
  const char* ug = (const char*)Up + (size_t)(ugrp * 4 + wave) * 32768;
  #pragma unroll
  for (int kk = 0; kk < 30; ++kk)
    gload_lds16(ug + kk * 1024 + lane * 16, upw + kk * 1024 + lane * 16);
  bf16x8 u30 = *(const bf16x8*)(ug + 30 * 1024 + lane * 16);
  bf16x8 u31 = *(const bf16x8*)(ug + 31 * 1024 + lane * 16);

  const size_t GSTRIDE = (size_t)SS * 4 * 64 * 256;   // per-gate stride
  const unsigned short* xp = xproj + (((size_t)rgrp * 64 + ugrp) * 256 + tid);
  const int hnidx = ((rgrp * 32 + (unit >> 5)) * 64 + ((unit >> 3) & 3) * 16 + r) * 8 + (unit & 7);
  unsigned int* myflags = bar + rgrp * 64;     // 64 dwords, one per producer
  float c = 0.f;
  unsigned short xv0 = xp[0], xv1 = xp[GSTRIDE], xv2 = xp[2 * GSTRIDE], xv3 = xp[3 * GSTRIDE];

  asm volatile("s_waitcnt vmcnt(0)" ::: "memory");
  __builtin_amdgcn_sched_barrier(0);
  __syncthreads();

  const bf16x8* uv = (const bf16x8*)upw;
  f32x4 z4 = {0.f, 0.f, 0.f, 0.f};  // U @ h_{-1} = 0
  unsigned fv = 0;                   // last-seen flag value for this lane

  for (int t = 0; t < SS; ++t) {
    // gate-exchange: z4 (this wave's gate slice) -> zt
    #pragma unroll
    for (int j = 0; j < 4; ++j)
      zt[wave][(lane >> 4) * 4 + j][lane & 15] = z4[j];
    __syncthreads();

    float zi = zt[0][r][uc] + bf2f(xv0);
    float zf = zt[1][r][uc] + bf2f(xv1);
    float zg = zt[2][r][uc] + bf2f(xv2);
    float zo = zt[3][r][uc] + bf2f(xv3);
    float ig = 1.f / (1.f + __expf(-zi));
    float fg = 1.f / (1.f + __expf(-zf));
    float gg = 1.f - 2.f / (1.f + __expf(2.f * zg));
    float og = 1.f / (1.f + __expf(-zo));
    c = fg * c + ig * gg;
    float h = og * (1.f - 2.f / (1.f + __expf(2.f * c)));

    if (t == SS - 1) {
      out[((size_t)row * SS + t) * DD + unit] = h;
      const size_t S0 = (size_t)BB * SS * DD;
      out[S0 + (size_t)row * DD + unit] = h;                     // ht
      out[S0 + (size_t)BB * DD + (size_t)row * DD + unit] = c;   // ct
      break;
    }

    unsigned short* hn = (t & 1) ? h0 : h1;
    // agent-coherent h store (write-through; no dirty L2 line)
    __hip_atomic_store(hn + hnidx, f2bf(h), __ATOMIC_RELAXED, __HIP_MEMORY_SCOPE_AGENT);
    __syncthreads();  // per-thread vmcnt drain before barrier => release pattern
    if (tid == 0)     // uncontended per-producer flag, monotonic tag
      __hip_atomic_store(myflags + ugrp, (unsigned)(t + 1), __ATOMIC_RELAXED, __HIP_MEMORY_SCOPE_AGENT);
    // deferred work overlaps flag propagation:
    out[((size_t)row * SS + t) * DD + unit] = h;
    {
      const size_t o = (size_t)(t + 1) * 65536;   // 4*64*256 per t
      xv0 = xp[o];
      xv1 = xp[GSTRIDE + o];
      xv2 = xp[2 * GSTRIDE + o];
      xv3 = xp[3 * GSTRIDE + o];
    }

    // ---- incremental pipelined consumption of h_t ----
    const char* hb = (const char*)((t & 1) ? h0 : h1) + rgrp * 32768 + lane * 16;
    const unsigned tgt = (unsigned)(t + 1);
    f32x4 a0 = {0.f,0.f,0.f,0.f}, a1 = a0, a2 = a0, a3 = a0;
    #pragma unroll
    for (int b = 0; b < 4; ++b) {
      // wait until producers [16b, 16b+16) have stored (ballot over 64 flags)
      while ((( __ballot((int)(fv >= tgt)) >> (16 * b)) & 0xFFFFull) != 0xFFFFull)
        fv = __hip_atomic_load(myflags + lane, __ATOMIC_RELAXED, __HIP_MEMORY_SCOPE_AGENT);
      // issue 8 independent coherent A-fragment loads
      bf16x8 av0, av1, av2, av3, av4, av5, av6, av7;
      const char* hbb = hb + b * 8192;
      asm volatile("global_load_dwordx4 %0, %1, off sc0 sc1" : "=v"(av0) : "v"(hbb + 0 * 1024) : "memory");
      asm volatile("global_load_dwordx4 %0, %1, off sc0 sc1" : "=v"(av1) : "v"(hbb + 1 * 1024) : "memory");
      asm volatile("global_load_dwordx4 %0, %1, off sc0 sc1" : "=v"(av2) : "v"(hbb + 2 * 1024) : "memory");
      asm volatile("global_load_dwordx4 %0, %1, off sc0 sc1" : "=v"(av3) : "v"(hbb + 3 * 1024) : "memory");
      asm volatile("global_load_dwordx4 %0, %1, off sc0 sc1" : "=v"(av4) : "v"(hbb + 4 * 1024) : "memory");
      asm volatile("global_load_dwordx4 %0, %1, off sc0 sc1" : "=v"(av5) : "v"(hbb + 5 * 1024) : "memory");
      asm volatile("global_load_dwordx4 %0, %1, off sc0 sc1" : "=v"(av6) : "v"(hbb + 6 * 1024) : "memory");
      asm volatile("global_load_dwordx4 %0, %1, off sc0 sc1" : "=v"(av7) : "v"(hbb + 7 * 1024) : "memory");
      asm volatile("s_waitcnt vmcnt(0)" ::: "memory");
      __builtin_amdgcn_sched_barrier(0);
      const int k0 = b * 8;
      a0 = __builtin_amdgcn_mfma_f32_16x16x32_bf16(av0, (k0 + 0 < 30) ? uv[(k0 + 0) * 64 + lane] : ((k0 + 0 == 30) ? u30 : u31), a0, 0, 0, 0);
      a1 = __builtin_amdgcn_mfma_f32_16x16x32_bf16(av1, (k0 + 1 < 30) ? uv[(k0 + 1) * 64 + lane] : ((k0 + 1 == 30) ? u30 : u31), a1, 0, 0, 0);
      a2 = __builtin_amdgcn_mfma_f32_16x16x32_bf16(av2, (k0 + 2 < 30) ? uv[(k0 + 2) * 64 + lane] : ((k0 + 2 == 30) ? u30 : u31), a2, 0, 0, 0);
      a3 = __builtin_amdgcn_mfma_f32_16x16x32_bf16(av3, (k0 + 3 < 30) ? uv[(k0 + 3) * 64 + lane] : ((k0 + 3 == 30) ? u30 : u31), a3, 0, 0, 0);
      a0 = __builtin_amdgcn_mfma_f32_16x16x32_bf16(av4, (k0 + 4 < 30) ? uv[(k0 + 4) * 64 + lane] : ((k0 + 4 == 30) ? u30 : u31), a0, 0, 0, 0);
      a1 = __builtin_amdgcn_mfma_f32_16x16x32_bf16(av5, (k0 + 5 < 30) ? uv[(k0 + 5) * 64 + lane] : ((k0 + 5 == 30) ? u30 : u31), a1, 0, 0, 0);
      a2 = __builtin_amdgcn_mfma_f32_16x16x32_bf16(av6, (k0 + 6 < 30) ? uv[(k0 + 6) * 64 + lane] : ((k0 + 6 == 30) ? u30 : u31), a2, 0, 0, 0);
      a3 = __builtin_amdgcn_mfma_f32_16x16x32_bf16(av7, (k0 + 7 < 30) ? uv[(k0 + 7) * 64 + lane] : ((k0 + 7 == 30) ? u30 : u31), a3, 0, 0, 0);
    }
    z4 = (a0 + a1) + (a2 + a3);
  }
}

// ---- round-1 step kernel kept as ws-size fallback ----
template <bool XBF>
__global__ __launch_bounds__(256) void lstm_step(
    const unsigned short* __restrict__ xb, const float* __restrict__ xf,
    const unsigned short* __restrict__ Wt, const unsigned short* __restrict__ Ut,
    const float* __restrict__ bias, unsigned short* __restrict__ hbuf,
    float* __restrict__ cbuf, float* __restrict__ out, int t) {
  __shared__ float ztl[4][16][16];
  const int wg = blockIdx.x;
  const int ugrp = wg >> 2, rgrp = wg & 3;
  const int row0 = rgrp * 16;
  const int ucol0 = ugrp * 16;
  const int wave = threadIdx.x >> 6;
  const int lane = threadIdx.x & 63;
  const int k0 = (lane >> 4) * 8;
  const int gr = row0 + (lane & 15);
  const int cg = wave * DD + ucol0 + (lane & 15);

  const unsigned short* hp = hbuf + (size_t)(t & 1) * BB * DD + (size_t)gr * DD + k0;
  const unsigned short* wp = Wt + (size_t)cg * DD + k0;
  const unsigned short* up = Ut + (size_t)cg * DD + k0;

  f32x4 acc = {0.f, 0.f, 0.f, 0.f};
  if (XBF) {
    const unsigned short* xpp = xb + ((size_t)gr * SS + t) * DD + k0;
    #pragma unroll 8
    for (int kk = 0; kk < DD; kk += 32) {
      bf16x8 a = *(const bf16x8*)(xpp + kk);
      bf16x8 b = *(const bf16x8*)(wp + kk);
      acc = __builtin_amdgcn_mfma_f32_16x16x32_bf16(a, b, acc, 0, 0, 0);
    }
  } else {
    const float* xpp = xf + ((size_t)gr * SS + t) * DD + k0;
    #pragma unroll 4
    for (int kk = 0; kk < DD; kk += 32) {
      float4 v0 = *(const float4*)(xpp + kk);
      float4 v1 = *(const float4*)(xpp + kk + 4);
      bf16x8 a;
      a[0] = (short)f2bf(v0.x); a[1] = (short)f2bf(v0.y);
      a[2] = (short)f2bf(v0.z); a[3] = (short)f2bf(v0.w);
      a[4] = (short)f2bf(v1.x); a[5] = (short)f2bf(v1.y);
      a[6] = (short)f2bf(v1.z); a[7] = (short)f2bf(v1.w);
      bf16x8 b = *(const bf16x8*)(wp + kk);
      acc = __builtin_amdgcn_mfma_f32_16x16x32_bf16(a, b, acc, 0, 0, 0);
    }
  }
  #pragma unroll 8
  for (int kk = 0; kk < DD; kk += 32) {
    bf16x8 a = *(const bf16x8*)(hp + kk);
    bf16x8 b = *(const bf16x8*)(up + kk);
    acc = __builtin_amdgcn_mfma_f32_16x16x32_bf16(a, b, acc, 0, 0, 0);
  }

  float bv = bias[cg];
  #pragma unroll
  for (int j = 0; j < 4; ++j)
    ztl[wave][(lane >> 4) * 4 + j][lane & 15] = acc[j] + bv;
  __syncthreads();

  const int r = threadIdx.x >> 4, uc = threadIdx.x & 15;
  float zi = ztl[0][r][uc], zf = ztl[1][r][uc], zg = ztl[2][r][uc], zo = ztl[3][r][uc];
  float ig = 1.f / (1.f + __expf(-zi));
  float fg = 1.f / (1.f + __expf(-zf));
  float gg = tanhf(zg);
  float og = 1.f / (1.f + __expf(-zo));
  const int gidx = (row0 + r) * DD + ucol0 + uc;
  float c = fg * cbuf[gidx] + ig * gg;
  cbuf[gidx] = c;
  float h = og * tanhf(c);
  hbuf[(size_t)((t & 1) ^ 1) * BB * DD + gidx] = f2bf(h);
  out[((size_t)(row0 + r) * SS + t) * DD + ucol0 + uc] = h;
  if (t == SS - 1) {
    out[(size_t)BB * SS * DD + gidx] = h;
    out[(size_t)BB * SS * DD + BB * DD + gidx] = c;
  }
}

extern "C" void kernel_launch(void* const* d_in, const int* in_sizes, int n_in,
                              void* d_out, int out_size, void* d_ws, size_t ws_size,
                              hipStream_t stream) {
  const float* x = (const float*)d_in[0];
  const float* W = (const float*)d_in[1];
  const float* U = (const float*)d_in[2];
  const float* bias = (const float*)d_in[3];
  float* out = (float*)d_out;
  char* ws = (char*)d_ws;

  // layout: Wt | Ut | h0 | h1 | cbuf | bar | xb | Up | xproj
  const size_t oWt = 0;
  const size_t oUt = oWt + (size_t)G4 * DD * 2;
  const size_t oH0 = oUt + (size_t)G4 * DD * 2;
  const size_t oH1 = oH0 + (size_t)BB * DD * 2;
  const size_t oC  = oH1 + (size_t)BB * DD * 2;
  const size_t oBar = oC + (size_t)BB * DD * 4;
  const size_t oXb = oBar + 4096;
  const size_t oUp = oXb + (size_t)BB * SS * DD * 2;
  const size_t oXp = oUp + (size_t)G4 * DD * 2;
  const size_t needPersist = oXp + (size_t)SS * BB * G4 * 2;
  const size_t needR1x = oUp;

  unsigned short* Wt = (unsigned short*)(ws + oWt);
  unsigned short* Ut = (unsigned short*)(ws + oUt);
  unsigned short* h0 = (unsigned short*)(ws + oH0);
  unsigned short* h1 = (unsigned short*)(ws + oH1);
  float* cbuf = (float*)(ws + oC);
  unsigned int* bar = (unsigned int*)(ws + oBar);
  unsigned short* xb = (unsigned short*)(ws + oXb);
  unsigned short* Up = (unsigned short*)(ws + oUp);
  unsigned short* xproj = (unsigned short*)(ws + oXp);

  if (ws_size >= needPersist) {
    hipFuncSetAttribute((const void*)lstm_persist,
                        hipFuncAttributeMaxDynamicSharedMemorySize, 126976);
    hipMemsetAsync(h0, 0, (size_t)BB * DD * 2, stream);
    hipMemsetAsync(bar, 0, 4096, stream);
    cvt_transpose<<<dim3(32, 128, 2), 256, 0, stream>>>(W, U, Wt, Ut);
    pack_u<<<2048, 256, 0, stream>>>(Ut, Up);
    cvt_x<<<2048, 256, 0, stream>>>(x, xb, BB * SS * DD / 8);
    gemm_xproj<<<dim3(256, 32), 256, 0, stream>>>(xb, Wt, bias, xproj);
    lstm_persist<<<256, 256, 126976, stream>>>(xproj, Up, h0, h1, bar, out);
  } else {
    unsigned short* hbuf = h0;  // h0|h1 contiguous
    const bool xbf = ws_size >= needR1x;
    hipMemsetAsync(hbuf, 0, (size_t)2 * BB * DD * 2 + (size_t)BB * DD * 4, stream);
    cvt_transpose<<<dim3(32, 128, 2), 256, 0, stream>>>(W, U, Wt, Ut);
    if (xbf) cvt_x<<<2048, 256, 0, stream>>>(x, xb, BB * SS * DD / 8);
    for (int t = 0; t < SS; ++t) {
      if (xbf)
        lstm_step<true><<<256, 256, 0, stream>>>(xb, nullptr, Wt, Ut, bias, hbuf, cbuf, out, t);
      else
        lstm_step<false><<<256, 256, 0, stream>>>(nullptr, x, Wt, Ut, bias, hbuf, cbuf, out, t);
    }
  }
}

// Round 13
// 2323.453 us; speedup vs baseline: 1.1667x; 1.0007x over previous
//
#include <hip/hip_runtime.h>
#include <hip/hip_bf16.h>
#include <cstdint>
#include <cstddef>

#define BB 64
#define SS 512
#define DD 1024
#define G4 4096  // 4*units

typedef __attribute__((ext_vector_type(8))) short bf16x8;
typedef __attribute__((ext_vector_type(8))) unsigned short u16x8;
typedef __attribute__((ext_vector_type(4))) float f32x4;

static __device__ __forceinline__ unsigned short f2bf(float f) {
  union { float f; uint32_t u; } v; v.f = f;
  uint32_t u = v.u;
  return (unsigned short)((u + 0x7FFFu + ((u >> 16) & 1u)) >> 16);  // RTNE
}
static __device__ __forceinline__ float bf2f(unsigned short s) {
  union { uint32_t u; float f; } v; v.u = ((uint32_t)s) << 16; return v.f;
}

typedef __attribute__((address_space(1))) const unsigned int kGlbU32;
typedef __attribute__((address_space(3))) unsigned int kLdsU32;
static __device__ __forceinline__ void gload_lds16(const void* g, void* l) {
  __builtin_amdgcn_global_load_lds((kGlbU32*)g, (kLdsU32*)l, 16, 0, 0);
}

// ---- convert x (f32 -> bf16), vectorized ----
__global__ void cvt_x(const float* __restrict__ in, unsigned short* __restrict__ out, int n8) {
  for (int i = blockIdx.x * blockDim.x + threadIdx.x; i < n8; i += gridDim.x * blockDim.x) {
    const float4* pp = (const float4*)(in + (size_t)i * 8);
    float4 a = pp[0], b2 = pp[1];
    u16x8 o;
    o[0] = f2bf(a.x);  o[1] = f2bf(a.y);  o[2] = f2bf(a.z);  o[3] = f2bf(a.w);
    o[4] = f2bf(b2.x); o[5] = f2bf(b2.y); o[6] = f2bf(b2.z); o[7] = f2bf(b2.w);
    *(u16x8*)(out + (size_t)i * 8) = o;
  }
}

// ---- transpose-convert W,U: in[k][c] f32 -> out[c][k] bf16 ----
__global__ __launch_bounds__(256) void cvt_transpose(
    const float* __restrict__ Win, const float* __restrict__ Uin,
    unsigned short* __restrict__ Wt, unsigned short* __restrict__ Ut) {
  __shared__ float tile[32][33];
  const float* in = blockIdx.z ? Uin : Win;
  unsigned short* out = blockIdx.z ? Ut : Wt;
  int k0 = blockIdx.x * 32;
  int c0 = blockIdx.y * 32;
  int tc = threadIdx.x & 31, tr = threadIdx.x >> 5;
  #pragma unroll
  for (int j = 0; j < 32; j += 8)
    tile[tr + j][tc] = in[(size_t)(k0 + tr + j) * G4 + (c0 + tc)];
  __syncthreads();
  #pragma unroll
  for (int j = 0; j < 32; j += 8)
    out[(size_t)(c0 + tr + j) * DD + (k0 + tc)] = f2bf(tile[tc][tr + j]);
}

// ---- pack Ut[col][k] into MFMA B-fragment order ----
__global__ __launch_bounds__(256) void pack_u(const unsigned short* __restrict__ Ut,
                                              unsigned short* __restrict__ Up) {
  int tid = blockIdx.x * 256 + threadIdx.x;  // 64*4*32*64 = 524288 total
  int l = tid & 63;
  int kk = (tid >> 6) & 31;
  int g = (tid >> 11) & 3;
  int u = tid >> 13;
  int col = g * DD + u * 16 + (l & 15);
  int k = kk * 32 + (l >> 4) * 8;
  bf16x8 v = *(const bf16x8*)(Ut + (size_t)col * DD + k);
  *(bf16x8*)(Up + (size_t)tid * 8) = v;
}

// ---- xproj GEMM: m97-style global_load_lds staging, g-outermost packed out ----
// xproj layout: [g][t][rgrp][ugrp][(b&15)*16 + uc] bf16, bias folded.
__global__ __launch_bounds__(256) void gemm_xproj(
    const unsigned short* __restrict__ xb,   // bf16 [32768][1024]
    const unsigned short* __restrict__ Wt,   // bf16 [4096][1024]
    const float* __restrict__ bias,
    unsigned short* __restrict__ xproj) {
  __shared__ unsigned short As[128 * 64], Bs[128 * 64];  // 16 KB each
  const int tid = threadIdx.x;
  const int wave = tid >> 6, lane = tid & 63;
  const int wr = wave >> 1, wc = wave & 1;
  const int m0 = blockIdx.x * 128, n0 = blockIdx.y * 128;

  char* asb = (char*)As;
  char* bsb = (char*)Bs;

  const int srw = lane >> 3;                       // row within chunk stripe
  const int skb = (((lane & 7) ^ srw) << 4);       // pre-swizzled source k-byte

  f32x4 acc[4][4];
  #pragma unroll
  for (int m = 0; m < 4; ++m)
    #pragma unroll
    for (int n = 0; n < 4; ++n) acc[m][n] = (f32x4){0.f, 0.f, 0.f, 0.f};

  for (int kt = 0; kt < DD / 64; ++kt) {
    __syncthreads();  // previous tile's ds_reads complete before overwrite
    #pragma unroll
    for (int q = 0; q < 4; ++q) {
      const int c = wave * 4 + q;                  // chunk 0..15
      gload_lds16((const char*)xb + (size_t)(m0 + c * 8 + srw) * 2048 + kt * 128 + skb,
                  asb + c * 1024 + lane * 16);
      gload_lds16((const char*)Wt + (size_t)(n0 + c * 8 + srw) * 2048 + kt * 128 + skb,
                  bsb + c * 1024 + lane * 16);
    }
    asm volatile("s_waitcnt vmcnt(0)" ::: "memory");
    __builtin_amdgcn_sched_barrier(0);
    __syncthreads();

    #pragma unroll
    for (int kh = 0; kh < 2; ++kh) {
      bf16x8 af[4], bfr[4];
      const int kb = kh * 64 + (lane >> 4) * 16;
      #pragma unroll
      for (int m = 0; m < 4; ++m) {
        int row = wr * 64 + m * 16 + (lane & 15);
        af[m] = *(const bf16x8*)(asb + row * 128 + (kb ^ ((row & 7) << 4)));
        int coln = wc * 64 + m * 16 + (lane & 15);
        bfr[m] = *(const bf16x8*)(bsb + coln * 128 + (kb ^ ((coln & 7) << 4)));
      }
      #pragma unroll
      for (int m = 0; m < 4; ++m)
        #pragma unroll
        for (int n = 0; n < 4; ++n)
          acc[m][n] = __builtin_amdgcn_mfma_f32_16x16x32_bf16(af[m], bfr[n], acc[m][n], 0, 0, 0);
    }
  }

  // C-write: g-outermost packed layout; 16 lanes -> 32B contiguous
  #pragma unroll
  for (int n = 0; n < 4; ++n) {
    int col = n0 + wc * 64 + n * 16 + (lane & 15);
    int g = col >> 10, unit = col & 1023;
    int ugrp2 = unit >> 4, uc2 = unit & 15;
    float bv = bias[col];
    #pragma unroll
    for (int m = 0; m < 4; ++m) {
      #pragma unroll
      for (int j = 0; j < 4; ++j) {
        int mrow = m0 + wr * 64 + m * 16 + (lane >> 4) * 4 + j;
        int b = mrow >> 9, t2 = mrow & 511;
        size_t idx = ((((size_t)g * SS + t2) * 4 + (b >> 4)) * 64 + ugrp2) * 256
                     + (b & 15) * 16 + uc2;
        xproj[idx] = f2bf(acc[m][n][j] + bv);
      }
    }
  }
}

// ---- persistent recurrence kernel: 256 wgs (1/CU), U resident in LDS ----
// r12 base + COALESCED producer h-store: gate-element mapping chosen so the
// wg's 512B h-block is written tid-contiguous (wave = 128B contiguous):
//   row=(tid>>3)&15, uc=(tid>>7)*8+(tid&7);
//   hoff = rgrp*16384 + (ugrp>>1)*512 + (ugrp&1)*256 + tid   (algebra verified)
// Memory layout of h is UNCHANGED — consumption side identical to r7/r12.
// Dynamic LDS (124 KB): [0,122880) Up: 4 waves x 30 frags; [122880,+4K) zt.
__global__ __launch_bounds__(256, 1) void lstm_persist(
    const unsigned short* __restrict__ xproj,  // packed [g][t][rgrp][ugrp][256]
    const unsigned short* __restrict__ Up,     // packed B-frags
    unsigned short* __restrict__ h0,           // packed A-frags [4][32][64][8]
    unsigned short* __restrict__ h1,
    unsigned int* __restrict__ bar,            // flags[4][64] dwords, zeroed
    float* __restrict__ out) {
  extern __shared__ char smem[];
  const int bid = blockIdx.x;
  const int rgrp = (bid & 7) >> 1;             // XCD-pair-friendly mapping
  const int ugrp = (bid >> 3) * 2 + (bid & 1);
  const int tid = threadIdx.x;
  const int wave = tid >> 6, lane = tid & 63;
  // coalesced-store gate-element mapping (r9-verified):
  const int row = (tid >> 3) & 15;             // batch row within rgrp
  const int uc = (tid >> 7) * 8 + (tid & 7);   // unit within ugrp
  const int unit = ugrp * 16 + uc;
  const int grow = rgrp * 16 + row;            // global batch row

  char* upw = smem + wave * 30720;             // this wave's 30 U-frags
  float (*zt)[16][16] = (float (*)[16][16])(smem + 122880);

  // one-time: stage this wave's U fragments (30 to LDS, 2 to regs)
  const char* ug = (const char*)Up + (size_t)(ugrp * 4 + wave) * 32768;
  #pragma unroll
  for (int kk = 0; kk < 30; ++kk)
    gload_lds16(ug + kk * 1024 + lane * 16, upw + kk * 1024 + lane * 16);
  bf16x8 u30 = *(const bf16x8*)(ug + 30 * 1024 + lane * 16);
  bf16x8 u31 = *(const bf16x8*)(ug + 31 * 1024 + lane * 16);

  const size_t GSTRIDE = (size_t)SS * 4 * 64 * 256;   // per-gate stride
  const unsigned short* xp = xproj + (((size_t)rgrp * 64 + ugrp) * 256 + row * 16 + uc);
  const size_t hoff = (size_t)rgrp * 16384 + (size_t)(ugrp >> 1) * 512 +
                      (size_t)(ugrp & 1) * 256 + tid;
  unsigned int* myflags = bar + rgrp * 64;     // 64 dwords, one per producer
  float c = 0.f;
  unsigned short xv0 = xp[0], xv1 = xp[GSTRIDE], xv2 = xp[2 * GSTRIDE], xv3 = xp[3 * GSTRIDE];

  asm volatile("s_waitcnt vmcnt(0)" ::: "memory");
  __builtin_amdgcn_sched_barrier(0);
  __syncthreads();

  const bf16x8* uv = (const bf16x8*)upw;
  f32x4 z4 = {0.f, 0.f, 0.f, 0.f};  // U @ h_{-1} = 0
  unsigned fv = 0;                   // last-seen flag value for this lane

  for (int t = 0; t < SS; ++t) {
    // gate-exchange: z4 (this wave's gate slice) -> zt
    #pragma unroll
    for (int j = 0; j < 4; ++j)
      zt[wave][(lane >> 4) * 4 + j][lane & 15] = z4[j];
    __syncthreads();

    float zi = zt[0][row][uc] + bf2f(xv0);
    float zf = zt[1][row][uc] + bf2f(xv1);
    float zg = zt[2][row][uc] + bf2f(xv2);
    float zo = zt[3][row][uc] + bf2f(xv3);
    float ig = 1.f / (1.f + __expf(-zi));
    float fg = 1.f / (1.f + __expf(-zf));
    float gg = 1.f - 2.f / (1.f + __expf(2.f * zg));
    float og = 1.f / (1.f + __expf(-zo));
    c = fg * c + ig * gg;
    float h = og * (1.f - 2.f / (1.f + __expf(2.f * c)));

    if (t == SS - 1) {
      out[((size_t)grow * SS + t) * DD + unit] = h;
      const size_t S0 = (size_t)BB * SS * DD;
      out[S0 + (size_t)grow * DD + unit] = h;                     // ht
      out[S0 + (size_t)BB * DD + (size_t)grow * DD + unit] = c;   // ct
      break;
    }

    unsigned short* hn = (t & 1) ? h0 : h1;
    // agent-coherent h store — tid-contiguous: wave writes 128B coalesced
    __hip_atomic_store(hn + hoff, f2bf(h), __ATOMIC_RELAXED, __HIP_MEMORY_SCOPE_AGENT);
    __syncthreads();  // per-thread vmcnt drain before barrier => release pattern
    if (tid == 0)     // uncontended per-producer flag, monotonic tag
      __hip_atomic_store(myflags + ugrp, (unsigned)(t + 1), __ATOMIC_RELAXED, __HIP_MEMORY_SCOPE_AGENT);
    // deferred work overlaps flag propagation:
    out[((size_t)grow * SS + t) * DD + unit] = h;
    {
      const size_t o = (size_t)(t + 1) * 65536;   // 4*64*256 per t
      xv0 = xp[o];
      xv1 = xp[GSTRIDE + o];
      xv2 = xp[2 * GSTRIDE + o];
      xv3 = xp[3 * GSTRIDE + o];
    }

    // ---- incremental pipelined consumption of h_t (r7 structure, unchanged) ----
    const char* hb = (const char*)((t & 1) ? h0 : h1) + rgrp * 32768 + lane * 16;
    const unsigned tgt = (unsigned)(t + 1);
    f32x4 a0 = {0.f,0.f,0.f,0.f}, a1 = a0, a2 = a0, a3 = a0;
    #pragma unroll
    for (int b = 0; b < 4; ++b) {
      // wait until producers [16b, 16b+16) have stored (ballot over 64 flags)
      while ((( __ballot((int)(fv >= tgt)) >> (16 * b)) & 0xFFFFull) != 0xFFFFull)
        fv = __hip_atomic_load(myflags + lane, __ATOMIC_RELAXED, __HIP_MEMORY_SCOPE_AGENT);
      // issue 8 independent coherent A-fragment loads
      bf16x8 av0, av1, av2, av3, av4, av5, av6, av7;
      const char* hbb = hb + b * 8192;
      asm volatile("global_load_dwordx4 %0, %1, off sc0 sc1" : "=v"(av0) : "v"(hbb + 0 * 1024) : "memory");
      asm volatile("global_load_dwordx4 %0, %1, off sc0 sc1" : "=v"(av1) : "v"(hbb + 1 * 1024) : "memory");
      asm volatile("global_load_dwordx4 %0, %1, off sc0 sc1" : "=v"(av2) : "v"(hbb + 2 * 1024) : "memory");
      asm volatile("global_load_dwordx4 %0, %1, off sc0 sc1" : "=v"(av3) : "v"(hbb + 3 * 1024) : "memory");
      asm volatile("global_load_dwordx4 %0, %1, off sc0 sc1" : "=v"(av4) : "v"(hbb + 4 * 1024) : "memory");
      asm volatile("global_load_dwordx4 %0, %1, off sc0 sc1" : "=v"(av5) : "v"(hbb + 5 * 1024) : "memory");
      asm volatile("global_load_dwordx4 %0, %1, off sc0 sc1" : "=v"(av6) : "v"(hbb + 6 * 1024) : "memory");
      asm volatile("global_load_dwordx4 %0, %1, off sc0 sc1" : "=v"(av7) : "v"(hbb + 7 * 1024) : "memory");
      asm volatile("s_waitcnt vmcnt(0)" ::: "memory");
      __builtin_amdgcn_sched_barrier(0);
      const int k0 = b * 8;
      a0 = __builtin_amdgcn_mfma_f32_16x16x32_bf16(av0, (k0 + 0 < 30) ? uv[(k0 + 0) * 64 + lane] : ((k0 + 0 == 30) ? u30 : u31), a0, 0, 0, 0);
      a1 = __builtin_amdgcn_mfma_f32_16x16x32_bf16(av1, (k0 + 1 < 30) ? uv[(k0 + 1) * 64 + lane] : ((k0 + 1 == 30) ? u30 : u31), a1, 0, 0, 0);
      a2 = __builtin_amdgcn_mfma_f32_16x16x32_bf16(av2, (k0 + 2 < 30) ? uv[(k0 + 2) * 64 + lane] : ((k0 + 2 == 30) ? u30 : u31), a2, 0, 0, 0);
      a3 = __builtin_amdgcn_mfma_f32_16x16x32_bf16(av3, (k0 + 3 < 30) ? uv[(k0 + 3) * 64 + lane] : ((k0 + 3 == 30) ? u30 : u31), a3, 0, 0, 0);
      a0 = __builtin_amdgcn_mfma_f32_16x16x32_bf16(av4, (k0 + 4 < 30) ? uv[(k0 + 4) * 64 + lane] : ((k0 + 4 == 30) ? u30 : u31), a0, 0, 0, 0);
      a1 = __builtin_amdgcn_mfma_f32_16x16x32_bf16(av5, (k0 + 5 < 30) ? uv[(k0 + 5) * 64 + lane] : ((k0 + 5 == 30) ? u30 : u31), a1, 0, 0, 0);
      a2 = __builtin_amdgcn_mfma_f32_16x16x32_bf16(av6, (k0 + 6 < 30) ? uv[(k0 + 6) * 64 + lane] : ((k0 + 6 == 30) ? u30 : u31), a2, 0, 0, 0);
      a3 = __builtin_amdgcn_mfma_f32_16x16x32_bf16(av7, (k0 + 7 < 30) ? uv[(k0 + 7) * 64 + lane] : ((k0 + 7 == 30) ? u30 : u31), a3, 0, 0, 0);
    }
    z4 = (a0 + a1) + (a2 + a3);
  }
}

// ---- round-1 step kernel kept as ws-size fallback ----
template <bool XBF>
__global__ __launch_bounds__(256) void lstm_step(
    const unsigned short* __restrict__ xb, const float* __restrict__ xf,
    const unsigned short* __restrict__ Wt, const unsigned short* __restrict__ Ut,
    const float* __restrict__ bias, unsigned short* __restrict__ hbuf,
    float* __restrict__ cbuf, float* __restrict__ out, int t) {
  __shared__ float ztl[4][16][16];
  const int wg = blockIdx.x;
  const int ugrp = wg >> 2, rgrp = wg & 3;
  const int row0 = rgrp * 16;
  const int ucol0 = ugrp * 16;
  const int wave = threadIdx.x >> 6;
  const int lane = threadIdx.x & 63;
  const int k0 = (lane >> 4) * 8;
  const int gr = row0 + (lane & 15);
  const int cg = wave * DD + ucol0 + (lane & 15);

  const unsigned short* hp = hbuf + (size_t)(t & 1) * BB * DD + (size_t)gr * DD + k0;
  const unsigned short* wp = Wt + (size_t)cg * DD + k0;
  const unsigned short* up = Ut + (size_t)cg * DD + k0;

  f32x4 acc = {0.f, 0.f, 0.f, 0.f};
  if (XBF) {
    const unsigned short* xpp = xb + ((size_t)gr * SS + t) * DD + k0;
    #pragma unroll 8
    for (int kk = 0; kk < DD; kk += 32) {
      bf16x8 a = *(const bf16x8*)(xpp + kk);
      bf16x8 b = *(const bf16x8*)(wp + kk);
      acc = __builtin_amdgcn_mfma_f32_16x16x32_bf16(a, b, acc, 0, 0, 0);
    }
  } else {
    const float* xpp = xf + ((size_t)gr * SS + t) * DD + k0;
    #pragma unroll 4
    for (int kk = 0; kk < DD; kk += 32) {
      float4 v0 = *(const float4*)(xpp + kk);
      float4 v1 = *(const float4*)(xpp + kk + 4);
      bf16x8 a;
      a[0] = (short)f2bf(v0.x); a[1] = (short)f2bf(v0.y);
      a[2] = (short)f2bf(v0.z); a[3] = (short)f2bf(v0.w);
      a[4] = (short)f2bf(v1.x); a[5] = (short)f2bf(v1.y);
      a[6] = (short)f2bf(v1.z); a[7] = (short)f2bf(v1.w);
      bf16x8 b = *(const bf16x8*)(wp + kk);
      acc = __builtin_amdgcn_mfma_f32_16x16x32_bf16(a, b, acc, 0, 0, 0);
    }
  }
  #pragma unroll 8
  for (int kk = 0; kk < DD; kk += 32) {
    bf16x8 a = *(const bf16x8*)(hp + kk);
    bf16x8 b = *(const bf16x8*)(up + kk);
    acc = __builtin_amdgcn_mfma_f32_16x16x32_bf16(a, b, acc, 0, 0, 0);
  }

  float bv = bias[cg];
  #pragma unroll
  for (int j = 0; j < 4; ++j)
    ztl[wave][(lane >> 4) * 4 + j][lane & 15] = acc[j] + bv;
  __syncthreads();

  const int r = threadIdx.x >> 4, uc = threadIdx.x & 15;
  float zi = ztl[0][r][uc], zf = ztl[1][r][uc], zg = ztl[2][r][uc], zo = ztl[3][r][uc];
  float ig = 1.f / (1.f + __expf(-zi));
  float fg = 1.f / (1.f + __expf(-zf));
  float gg = tanhf(zg);
  float og = 1.f / (1.f + __expf(-zo));
  const int gidx = (row0 + r) * DD + ucol0 + uc;
  float c = fg * cbuf[gidx] + ig * gg;
  cbuf[gidx] = c;
  float h = og * tanhf(c);
  hbuf[(size_t)((t & 1) ^ 1) * BB * DD + gidx] = f2bf(h);
  out[((size_t)(row0 + r) * SS + t) * DD + ucol0 + uc] = h;
  if (t == SS - 1) {
    out[(size_t)BB * SS * DD + gidx] = h;
    out[(size_t)BB * SS * DD + BB * DD + gidx] = c;
  }
}

extern "C" void kernel_launch(void* const* d_in, const int* in_sizes, int n_in,
                              void* d_out, int out_size, void* d_ws, size_t ws_size,
                              hipStream_t stream) {
  const float* x = (const float*)d_in[0];
  const float* W = (const float*)d_in[1];
  const float* U = (const float*)d_in[2];
  const float* bias = (const float*)d_in[3];
  float* out = (float*)d_out;
  char* ws = (char*)d_ws;

  // layout: Wt | Ut | h0 | h1 | cbuf | bar | xb | Up | xproj
  const size_t oWt = 0;
  const size_t oUt = oWt + (size_t)G4 * DD * 2;
  const size_t oH0 = oUt + (size_t)G4 * DD * 2;
  const size_t oH1 = oH0 + (size_t)BB * DD * 2;
  const size_t oC  = oH1 + (size_t)BB * DD * 2;
  const size_t oBar = oC + (size_t)BB * DD * 4;
  const size_t oXb = oBar + 4096;
  const size_t oUp = oXb + (size_t)BB * SS * DD * 2;
  const size_t oXp = oUp + (size_t)G4 * DD * 2;
  const size_t needPersist = oXp + (size_t)SS * BB * G4 * 2;
  const size_t needR1x = oUp;

  unsigned short* Wt = (unsigned short*)(ws + oWt);
  unsigned short* Ut = (unsigned short*)(ws + oUt);
  unsigned short* h0 = (unsigned short*)(ws + oH0);
  unsigned short* h1 = (unsigned short*)(ws + oH1);
  float* cbuf = (float*)(ws + oC);
  unsigned int* bar = (unsigned int*)(ws + oBar);
  unsigned short* xb = (unsigned short*)(ws + oXb);
  unsigned short* Up = (unsigned short*)(ws + oUp);
  unsigned short* xproj = (unsigned short*)(ws + oXp);

  if (ws_size >= needPersist) {
    hipFuncSetAttribute((const void*)lstm_persist,
                        hipFuncAttributeMaxDynamicSharedMemorySize, 126976);
    hipMemsetAsync(h0, 0, (size_t)BB * DD * 2, stream);
    hipMemsetAsync(bar, 0, 4096, stream);
    cvt_transpose<<<dim3(32, 128, 2), 256, 0, stream>>>(W, U, Wt, Ut);
    pack_u<<<2048, 256, 0, stream>>>(Ut, Up);
    cvt_x<<<2048, 256, 0, stream>>>(x, xb, BB * SS * DD / 8);
    gemm_xproj<<<dim3(256, 32), 256, 0, stream>>>(xb, Wt, bias, xproj);
    lstm_persist<<<256, 256, 126976, stream>>>(xproj, Up, h0, h1, bar, out);
  } else {
    unsigned short* hbuf = h0;  // h0|h1 contiguous
    const bool xbf = ws_size >= needR1x;
    hipMemsetAsync(hbuf, 0, (size_t)2 * BB * DD * 2 + (size_t)BB * DD * 4, stream);
    cvt_transpose<<<dim3(32, 128, 2), 256, 0, stream>>>(W, U, Wt, Ut);
    if (xbf) cvt_x<<<2048, 256, 0, stream>>>(x, xb, BB * SS * DD / 8);
    for (int t = 0; t < SS; ++t) {
      if (xbf)
        lstm_step<true><<<256, 256, 0, stream>>>(xb, nullptr, Wt, Ut, bias, hbuf, cbuf, out, t);
      else
        lstm_step<false><<<256, 256, 0, stream>>>(nullptr, x, Wt, Ut, bias, hbuf, cbuf, out, t);
    }
  }
}